// Round 6
// baseline (490.934 us; speedup 1.0000x reference)
//
#include <hip/hip_runtime.h>
#include <hip/hip_bf16.h>
#include <stdint.h>

#define B_ 4
#define H_ 16
#define L_ 2048
#define D_ 64
#define BH (B_ * H_)
#define NT (BH * 32)   // number of 64x64 tiles per tensor = 2048

typedef __attribute__((ext_vector_type(8))) short short8;
typedef __attribute__((ext_vector_type(4))) float f32x4;

__device__ __forceinline__ short b16(float f) {
  __hip_bfloat16 h = __float2bfloat16(f);
  return __builtin_bit_cast(short, h);
}

// ---- merged prepass ----
// blocks [0, NT):    K [bh][k][d] fp32 -> Kb: per (bh,kt) 64x64 bf16 swizzled tile image
// blocks [NT, 2NT):  V [bh][k][d] fp32 -> Vb: per (bh,kt) [d][k] bf16 swizzled tile image
__global__ __launch_bounds__(256) void prep_kernel(const float* __restrict__ K,
                                                   const float* __restrict__ V,
                                                   unsigned short* __restrict__ Kb,
                                                   unsigned short* __restrict__ Vb) {
  __shared__ unsigned short lds[64 * 68];
  int bid = blockIdx.x;
  int t   = threadIdx.x;
  if (bid < NT) {
    const float* src = K + (size_t)bid * 64 * D_;
    unsigned short* dst = Kb + (size_t)bid * 4096;
#pragma unroll
    for (int i = 0; i < 4; ++i) {
      int f4  = i * 256 + t;
      int row = f4 >> 4;
      int c4  = (f4 & 15) << 2;
      float4 v = *reinterpret_cast<const float4*>(src + row * D_ + c4);
      ushort4 u;
      u.x = (unsigned short)b16(v.x);
      u.y = (unsigned short)b16(v.y);
      u.z = (unsigned short)b16(v.z);
      u.w = (unsigned short)b16(v.w);
      *reinterpret_cast<ushort4*>(&dst[row * 64 + (c4 ^ ((row & 7) << 3))]) = u;
    }
  } else {
    bid -= NT;
    const float* src = V + (size_t)bid * 64 * D_;
#pragma unroll
    for (int i = 0; i < 4; ++i) {
      int f4  = i * 256 + t;
      int row = f4 >> 4;
      int c4  = (f4 & 15) << 2;
      float4 v = *reinterpret_cast<const float4*>(src + row * D_ + c4);
      ushort4 u;
      u.x = (unsigned short)b16(v.x);
      u.y = (unsigned short)b16(v.y);
      u.z = (unsigned short)b16(v.z);
      u.w = (unsigned short)b16(v.w);
      *reinterpret_cast<ushort4*>(&lds[row * 68 + c4]) = u;
    }
    __syncthreads();
    unsigned short* dst = Vb + (size_t)bid * 4096;
#pragma unroll
    for (int i = 0; i < 4; ++i) {
      int g  = i * 256 + t;
      int r  = g >> 4;          // d-row
      int c4 = (g & 15) << 2;   // k-cols
      ushort4 u;
      u.x = lds[(c4 + 0) * 68 + r];
      u.y = lds[(c4 + 1) * 68 + r];
      u.z = lds[(c4 + 2) * 68 + r];
      u.w = lds[(c4 + 3) * 68 + r];
      *reinterpret_cast<ushort4*>(&dst[r * 64 + (c4 ^ ((r & 7) << 3))]) = u;
    }
  }
}

// ---- fused sigmoid-attention: 2 barriers/iter, reg-prefetch with mask-first ordering ----
__global__ __launch_bounds__(256, 4) void attn5_kernel(
    const float* __restrict__ Q, const int* __restrict__ M,
    const unsigned short* __restrict__ Kb, const unsigned short* __restrict__ Vb,
    float* __restrict__ O, float* __restrict__ A) {
  __shared__ __align__(16) unsigned short Kl[2][4096];
  __shared__ __align__(16) unsigned short Vl[2][4096];
  __shared__ __align__(16) unsigned short Pl[4096];

  // XCD-aware decode (R3's proven mapping): co-resident window shares both
  // mask stripes (across h) and K/V (across qt).
  int wg  = blockIdx.x;
  int xcd = wg & 7;
  int j   = wg >> 3;
  int g   = xcd * 16 + (j & 15);
  int b   = g >> 5;
  int qt  = g & 31;
  int h   = j >> 4;
  int bh  = b * 16 + h;

  int t    = threadIdx.x;
  int lane = t & 63;
  int w    = t >> 6;
  int wr   = w >> 1;
  int wc   = w & 1;
  int lr   = lane & 15;
  int lg   = lane >> 4;

  // Q fragments, temperature folded in
  short8 qf[2][2];
  const float* qbase = Q + ((size_t)bh * L_ + (size_t)qt * 64 + wr * 32) * D_;
#pragma unroll
  for (int m = 0; m < 2; ++m) {
#pragma unroll
    for (int ks = 0; ks < 2; ++ks) {
      const float4* p = reinterpret_cast<const float4*>(qbase + (m * 16 + lr) * D_ + ks * 32 + lg * 8);
      float4 a = p[0], c = p[1];
      qf[m][ks] = (short8){b16(a.x * 0.125f), b16(a.y * 0.125f), b16(a.z * 0.125f), b16(a.w * 0.125f),
                           b16(c.x * 0.125f), b16(c.y * 0.125f), b16(c.z * 0.125f), b16(c.w * 0.125f)};
    }
  }

  f32x4 o[2][2] = {};
  const int* mbase = M + (size_t)b * L_ * L_;
  float* abase = A + (size_t)bh * L_ * L_;
  const unsigned short* kb = Kb + (size_t)(bh * 32) * 4096;
  const unsigned short* vb = Vb + (size_t)(bh * 32) * 4096;
  int qrow = qt * 64 + wr * 32;

  // linear stage offsets (tile images are pre-swizzled)
  int s0 = t * 8;          // ushort index of first 16B chunk
  int s1 = t * 8 + 2048;   // second 16B chunk

  uint4 kpre[2], vpre[2];

  // prologue: tile 0 -> LDS buf 0
  kpre[0] = *reinterpret_cast<const uint4*>(kb + s0);
  kpre[1] = *reinterpret_cast<const uint4*>(kb + s1);
  vpre[0] = *reinterpret_cast<const uint4*>(vb + s0);
  vpre[1] = *reinterpret_cast<const uint4*>(vb + s1);
  *reinterpret_cast<uint4*>(&Kl[0][s0]) = kpre[0];
  *reinterpret_cast<uint4*>(&Kl[0][s1]) = kpre[1];
  *reinterpret_cast<uint4*>(&Vl[0][s0]) = vpre[0];
  *reinterpret_cast<uint4*>(&Vl[0][s1]) = vpre[1];
  __syncthreads();

  for (int ki = 0; ki < 32; ++ki) {
    int cur = ki & 1;
    int k0  = ki * 64;

    // (1) mask loads FIRST (sigmoid's vmcnt wait then skips the prefetch loads)
    int4 mv[2][2];
#pragma unroll
    for (int m = 0; m < 2; ++m)
#pragma unroll
      for (int n = 0; n < 2; ++n)
        mv[m][n] = *reinterpret_cast<const int4*>(
            mbase + (size_t)(qrow + m * 16 + lr) * L_ + k0 + wc * 32 + n * 16 + lg * 4);

    // (2) next-tile prefetch issues (drain at the ds_write after PV)
    if (ki + 1 < 32) {
      const unsigned short* ks_ = kb + (size_t)(ki + 1) * 4096;
      const unsigned short* vs_ = vb + (size_t)(ki + 1) * 4096;
      kpre[0] = *reinterpret_cast<const uint4*>(ks_ + s0);
      kpre[1] = *reinterpret_cast<const uint4*>(ks_ + s1);
      vpre[0] = *reinterpret_cast<const uint4*>(vs_ + s0);
      vpre[1] = *reinterpret_cast<const uint4*>(vs_ + s1);
    }

    // (3) S^T = K Q^T : lane holds 4 consecutive k for one q
    f32x4 s[2][2] = {};
#pragma unroll
    for (int ks = 0; ks < 2; ++ks) {
      short8 kf[2];
#pragma unroll
      for (int n = 0; n < 2; ++n) {
        int row = wc * 32 + n * 16 + lr;
        int col = ks * 32 + lg * 8;
        kf[n] = *reinterpret_cast<const short8*>(&Kl[cur][row * 64 + (col ^ ((row & 7) << 3))]);
      }
#pragma unroll
      for (int m = 0; m < 2; ++m)
#pragma unroll
        for (int n = 0; n < 2; ++n)
          s[m][n] = __builtin_amdgcn_mfma_f32_16x16x32_bf16(kf[n], qf[m][ks], s[m][n], 0, 0, 0);
    }

    // (4) mask + sigmoid; attn f32x4 nt-store; P ushort4 LDS write
#pragma unroll
    for (int m = 0; m < 2; ++m) {
#pragma unroll
      for (int n = 0; n < 2; ++n) {
        f32x4 f;
        ushort4 u;
#pragma unroll
        for (int r = 0; r < 4; ++r) {
          float sv = s[m][n][r];
          float e  = __builtin_amdgcn_exp2f(sv * -1.44269504f);
          float at = ((&mv[m][n].x)[r] != 0)
                         ? __builtin_amdgcn_rcpf(1.0f + e)
                         : 0.0f;
          f[r] = at;
          (&u.x)[r] = (unsigned short)b16(at);
        }
        __builtin_nontemporal_store(f, reinterpret_cast<f32x4*>(
            abase + (size_t)(qrow + m * 16 + lr) * L_ + k0 + wc * 32 + n * 16 + lg * 4));
        int q  = wr * 32 + m * 16 + lr;
        int kl = wc * 32 + n * 16 + lg * 4;
        *reinterpret_cast<ushort4*>(&Pl[q * 64 + (kl ^ ((q & 7) << 3))]) = u;
      }
    }
    __syncthreads();  // B2: P visible

    // (5) O += P V
#pragma unroll
    for (int ks = 0; ks < 2; ++ks) {
      short8 pf[2], vf[2];
#pragma unroll
      for (int m = 0; m < 2; ++m) {
        int row = wr * 32 + m * 16 + lr;
        int col = ks * 32 + lg * 8;
        pf[m] = *reinterpret_cast<const short8*>(&Pl[row * 64 + (col ^ ((row & 7) << 3))]);
      }
#pragma unroll
      for (int n = 0; n < 2; ++n) {
        int row = wc * 32 + n * 16 + lr;
        int col = ks * 32 + lg * 8;
        vf[n] = *reinterpret_cast<const short8*>(&Vl[cur][row * 64 + (col ^ ((row & 7) << 3))]);
      }
#pragma unroll
      for (int m = 0; m < 2; ++m)
#pragma unroll
        for (int n = 0; n < 2; ++n)
          o[m][n] = __builtin_amdgcn_mfma_f32_16x16x32_bf16(pf[m], vf[n], o[m][n], 0, 0, 0);
    }

    // (6) write next tile -> other LDS buffer (prefetch long arrived)
    if (ki + 1 < 32) {
      *reinterpret_cast<uint4*>(&Kl[cur ^ 1][s0]) = kpre[0];
      *reinterpret_cast<uint4*>(&Kl[cur ^ 1][s1]) = kpre[1];
      *reinterpret_cast<uint4*>(&Vl[cur ^ 1][s0]) = vpre[0];
      *reinterpret_cast<uint4*>(&Vl[cur ^ 1][s1]) = vpre[1];
    }
    __syncthreads();  // B_end: stage writes visible for next iter
  }

  // ---- epilogue: write O ----
  float* obase = O + ((size_t)bh * L_ + (size_t)qt * 64 + wr * 32) * D_;
#pragma unroll
  for (int m = 0; m < 2; ++m)
#pragma unroll
    for (int n = 0; n < 2; ++n)
#pragma unroll
      for (int r = 0; r < 4; ++r)
        __builtin_nontemporal_store(o[m][n][r],
            &obase[(m * 16 + lg * 4 + r) * D_ + wc * 32 + n * 16 + lr]);
}

extern "C" void kernel_launch(void* const* d_in, const int* in_sizes, int n_in,
                              void* d_out, int out_size, void* d_ws, size_t ws_size,
                              hipStream_t stream) {
  (void)in_sizes; (void)n_in; (void)out_size; (void)ws_size;
  const float* Q = (const float*)d_in[0];
  const float* K = (const float*)d_in[1];
  const float* V = (const float*)d_in[2];
  const int*   M = (const int*)d_in[3];
  float* O = (float*)d_out;
  float* A = (float*)d_out + (size_t)BH * L_ * D_;
  unsigned short* Kb = (unsigned short*)d_ws;                    // 16.8 MB
  unsigned short* Vb = (unsigned short*)d_ws + (size_t)NT * 4096; // 16.8 MB

  prep_kernel<<<2 * NT, 256, 0, stream>>>(K, V, Kb, Vb);
  attn5_kernel<<<NT, 256, 0, stream>>>(Q, M, Kb, Vb, O, A);
}

// Round 7
// 318.850 us; speedup vs baseline: 1.5397x; 1.5397x over previous
//
#include <hip/hip_runtime.h>
#include <hip/hip_bf16.h>
#include <stdint.h>

#define B_ 4
#define H_ 16
#define L_ 2048
#define D_ 64
#define BH (B_ * H_)

typedef __attribute__((ext_vector_type(8))) short short8;
typedef __attribute__((ext_vector_type(4))) float f32x4;

__device__ __forceinline__ short b16(float f) {
  __hip_bfloat16 h = __float2bfloat16(f);
  return __builtin_bit_cast(short, h);
}
__device__ __forceinline__ unsigned int pkbf16(float lo, float hi) {
  return (unsigned int)(unsigned short)b16(lo) |
         ((unsigned int)(unsigned short)b16(hi) << 16);
}

// ---- prepass: V [bh][k][d] fp32 -> Vt [bh][d][k] bf16 (transposed) ----
__global__ __launch_bounds__(256) void vt_kernel(const float* __restrict__ V,
                                                 unsigned short* __restrict__ Vt) {
  __shared__ unsigned short lds[64 * 68];
  int bid = blockIdx.x;
  int bh  = bid >> 5;
  int kt  = bid & 31;
  int t   = threadIdx.x;
  const float* vsrc = V + ((size_t)bh * L_ + (size_t)kt * 64) * D_;
#pragma unroll
  for (int i = 0; i < 4; ++i) {
    int f4  = i * 256 + t;
    int row = f4 >> 4;
    int c4  = (f4 & 15) << 2;
    float4 v = *reinterpret_cast<const float4*>(vsrc + row * D_ + c4);
    ushort4 u;
    u.x = (unsigned short)b16(v.x);
    u.y = (unsigned short)b16(v.y);
    u.z = (unsigned short)b16(v.z);
    u.w = (unsigned short)b16(v.w);
    *reinterpret_cast<ushort4*>(&lds[row * 68 + c4]) = u;
  }
  __syncthreads();
  unsigned short* dst = Vt + (size_t)bh * D_ * L_ + (size_t)kt * 64;
#pragma unroll
  for (int i = 0; i < 8; ++i) {
    int c  = i * 256 + t;
    int d  = c >> 5;
    int k2 = (c & 31) * 2;
    unsigned int lo = lds[(k2 + 0) * 68 + d];
    unsigned int hi = lds[(k2 + 1) * 68 + d];
    *reinterpret_cast<unsigned int*>(dst + d * L_ + k2) = lo | (hi << 16);
  }
}

// ---- fused sigmoid-attention: wave = 16-q strip x full 64 k; P stays in-wave
// (bpermute repack), 1 barrier/iter, dbuf K/V ----
__global__ __launch_bounds__(256, 4) void attn6_kernel(
    const float* __restrict__ Q, const float* __restrict__ K,
    const int* __restrict__ M, const unsigned short* __restrict__ Vt,
    float* __restrict__ O, float* __restrict__ A) {
  __shared__ unsigned short Kl[2][4096];
  __shared__ unsigned short Vl[2][4096];

  // XCD-aware decode (R3's proven mapping)
  int wg  = blockIdx.x;
  int xcd = wg & 7;
  int j   = wg >> 3;
  int g   = xcd * 16 + (j & 15);
  int b   = g >> 5;
  int qt  = g & 31;
  int h   = j >> 4;
  int bh  = b * 16 + h;

  int t    = threadIdx.x;
  int lane = t & 63;
  int w    = t >> 6;
  int lr   = lane & 15;
  int lg   = lane >> 4;
  int qrow0 = qt * 64 + w * 16;  // this wave's global q base

  // Q fragments (B-operand): q = qrow0 + lr, d = ks*32 + lg*8, temp folded
  short8 qf[2];
  {
    const float* qb = Q + ((size_t)bh * L_ + qrow0 + lr) * D_;
#pragma unroll
    for (int ks = 0; ks < 2; ++ks) {
      const float4* p = reinterpret_cast<const float4*>(qb + ks * 32 + lg * 8);
      float4 a = p[0], c = p[1];
      qf[ks] = (short8){b16(a.x * 0.125f), b16(a.y * 0.125f), b16(a.z * 0.125f), b16(a.w * 0.125f),
                        b16(c.x * 0.125f), b16(c.y * 0.125f), b16(c.z * 0.125f), b16(c.w * 0.125f)};
    }
  }

  f32x4 o[4] = {};  // O[q = lg*4+r][d = n2*16 + lr]
  const int* mbase = M + (size_t)b * L_ * L_;
  float* abase = A + (size_t)bh * L_ * L_;
  const float* kbase0 = K + (size_t)bh * L_ * D_;
  const unsigned short* vbase0 = Vt + (size_t)bh * D_ * L_;

  // staging geometry (per thread, same as R3)
  int krow[4], kc4[4];
#pragma unroll
  for (int i = 0; i < 4; ++i) {
    int f4  = i * 256 + t;
    krow[i] = f4 >> 4;
    kc4[i]  = (f4 & 15) << 2;
  }
  int vrow[2], vc0[2];
#pragma unroll
  for (int i = 0; i < 2; ++i) {
    int gi  = i * 256 + t;
    vrow[i] = gi >> 3;
    vc0[i]  = (gi & 7) << 3;
  }

  // bpermute source-lane byte indices (two sources per lane, per i>>1)
  int srcA = (lr + 16 * (2 * (lane >> 4 & 1))) << 2;  // i>>1 == 0
  int srcB = srcA + 64;                                // i>>1 == 1
  bool hin = (lg & 2) != 0;                            // select n = 2ks+1

  float4 kreg[4];
  uint4  vreg[2];

  // prologue: tile 0 -> LDS buf 0
#pragma unroll
  for (int i = 0; i < 4; ++i)
    kreg[i] = *reinterpret_cast<const float4*>(kbase0 + krow[i] * D_ + kc4[i]);
#pragma unroll
  for (int i = 0; i < 2; ++i)
    vreg[i] = *reinterpret_cast<const uint4*>(vbase0 + (size_t)vrow[i] * L_ + vc0[i]);
#pragma unroll
  for (int i = 0; i < 4; ++i) {
    ushort4 u;
    u.x = (unsigned short)b16(kreg[i].x);
    u.y = (unsigned short)b16(kreg[i].y);
    u.z = (unsigned short)b16(kreg[i].z);
    u.w = (unsigned short)b16(kreg[i].w);
    *reinterpret_cast<ushort4*>(&Kl[0][krow[i] * 64 + (kc4[i] ^ ((krow[i] & 7) << 3))]) = u;
  }
#pragma unroll
  for (int i = 0; i < 2; ++i)
    *reinterpret_cast<uint4*>(&Vl[0][vrow[i] * 64 + (vc0[i] ^ ((vrow[i] & 7) << 3))]) = vreg[i];
  __syncthreads();

  for (int ki = 0; ki < 32; ++ki) {
    int cur = ki & 1;
    int k0  = ki * 64;

    // (1) mask loads FIRST: one int4 per k-16-block n
    int4 mv[4];
#pragma unroll
    for (int n = 0; n < 4; ++n)
      mv[n] = *reinterpret_cast<const int4*>(
          mbase + (size_t)(qrow0 + lr) * L_ + k0 + n * 16 + lg * 4);

    // (2) next-tile staging loads (drain at ds_write after PV)
    if (ki + 1 < 32) {
      const float* ksrc = kbase0 + (size_t)(k0 + 64) * D_;
      const unsigned short* vsrc = vbase0 + k0 + 64;
#pragma unroll
      for (int i = 0; i < 4; ++i)
        kreg[i] = *reinterpret_cast<const float4*>(ksrc + krow[i] * D_ + kc4[i]);
#pragma unroll
      for (int i = 0; i < 2; ++i)
        vreg[i] = *reinterpret_cast<const uint4*>(vsrc + (size_t)vrow[i] * L_ + vc0[i]);
    }

    // (3) S^T = K Q^T : s[n] row k = n*16+lg*4+r, col q = lr
    f32x4 s[4] = {};
#pragma unroll
    for (int ks = 0; ks < 2; ++ks) {
#pragma unroll
      for (int n = 0; n < 4; ++n) {
        int row = n * 16 + lr;
        int col = ks * 32 + lg * 8;
        short8 kf = *reinterpret_cast<const short8*>(&Kl[cur][row * 64 + (col ^ ((row & 7) << 3))]);
        s[n] = __builtin_amdgcn_mfma_f32_16x16x32_bf16(kf, qf[ks], s[n], 0, 0, 0);
      }
    }

    // (4) mask + sigmoid; attn f32x4 nt-store; pack P to bf16 dwords c[n][d2]
    unsigned int c[4][2];
#pragma unroll
    for (int n = 0; n < 4; ++n) {
      f32x4 f;
#pragma unroll
      for (int r = 0; r < 4; ++r) {
        float sv = s[n][r];
        float e  = __builtin_amdgcn_exp2f(sv * -1.44269504f);
        float at = ((&mv[n].x)[r] != 0) ? __builtin_amdgcn_rcpf(1.0f + e) : 0.0f;
        f[r] = at;
      }
      __builtin_nontemporal_store(f, reinterpret_cast<f32x4*>(
          abase + (size_t)(qrow0 + lr) * L_ + k0 + n * 16 + lg * 4));
      c[n][0] = pkbf16(f[0], f[1]);
      c[n][1] = pkbf16(f[2], f[3]);
    }

    // (5) intra-wave repack: pf[ks].w[i] = c[2ks + (lg>>1)][i&1] from lane srcA/srcB
    short8 pf[2];
#pragma unroll
    for (int ks = 0; ks < 2; ++ks) {
      unsigned int wv[4];
#pragma unroll
      for (int i = 0; i < 4; ++i) {
        int idx = (i >> 1) ? srcB : srcA;
        int lo = __builtin_amdgcn_ds_bpermute(idx, (int)c[2 * ks][i & 1]);
        int hi = __builtin_amdgcn_ds_bpermute(idx, (int)c[2 * ks + 1][i & 1]);
        wv[i] = (unsigned int)(hin ? hi : lo);
      }
      uint4 u4 = {wv[0], wv[1], wv[2], wv[3]};
      pf[ks] = __builtin_bit_cast(short8, u4);
    }

    // (6) O += P V : o[n2] rows q = lg*4+r, cols d = n2*16+lr
#pragma unroll
    for (int ks = 0; ks < 2; ++ks) {
#pragma unroll
      for (int n2 = 0; n2 < 4; ++n2) {
        int row = n2 * 16 + lr;
        int col = ks * 32 + lg * 8;
        short8 vf = *reinterpret_cast<const short8*>(&Vl[cur][row * 64 + (col ^ ((row & 7) << 3))]);
        o[n2] = __builtin_amdgcn_mfma_f32_16x16x32_bf16(pf[ks], vf, o[n2], 0, 0, 0);
      }
    }

    // (7) write next tile regs -> other LDS buffer
    if (ki + 1 < 32) {
#pragma unroll
      for (int i = 0; i < 4; ++i) {
        ushort4 u;
        u.x = (unsigned short)b16(kreg[i].x);
        u.y = (unsigned short)b16(kreg[i].y);
        u.z = (unsigned short)b16(kreg[i].z);
        u.w = (unsigned short)b16(kreg[i].w);
        *reinterpret_cast<ushort4*>(&Kl[cur ^ 1][krow[i] * 64 + (kc4[i] ^ ((krow[i] & 7) << 3))]) = u;
      }
#pragma unroll
      for (int i = 0; i < 2; ++i)
        *reinterpret_cast<uint4*>(&Vl[cur ^ 1][vrow[i] * 64 + (vc0[i] ^ ((vrow[i] & 7) << 3))]) = vreg[i];
    }
    __syncthreads();  // single barrier: buf^1 writes visible; cur readers done
  }

  // ---- epilogue: write O ----
  float* obase = O + ((size_t)bh * L_ + qrow0) * D_;
#pragma unroll
  for (int n2 = 0; n2 < 4; ++n2)
#pragma unroll
    for (int r = 0; r < 4; ++r)
      __builtin_nontemporal_store(o[n2][r],
          &obase[(lg * 4 + r) * D_ + n2 * 16 + lr]);
}

extern "C" void kernel_launch(void* const* d_in, const int* in_sizes, int n_in,
                              void* d_out, int out_size, void* d_ws, size_t ws_size,
                              hipStream_t stream) {
  (void)in_sizes; (void)n_in; (void)out_size; (void)ws_size;
  const float* Q = (const float*)d_in[0];
  const float* K = (const float*)d_in[1];
  const float* V = (const float*)d_in[2];
  const int*   M = (const int*)d_in[3];
  float* O = (float*)d_out;
  float* A = (float*)d_out + (size_t)BH * L_ * D_;
  unsigned short* Vt = (unsigned short*)d_ws;  // 16.8 MB scratch

  vt_kernel<<<BH * 32, 256, 0, stream>>>(V, Vt);
  attn6_kernel<<<BH * 32, 256, 0, stream>>>(Q, K, M, Vt, O, A);
}